// Round 5
// baseline (1627.917 us; speedup 1.0000x reference)
//
#include <hip/hip_runtime.h>
#include <hip/hip_bf16.h>
#include <math.h>

// ---------------------------------------------------------------------------
// GCN link-prediction encoder: 6 GCN layers + dot-product decoder.
// R5: (a) int-only histogram atomics (deg/dinv from sorted pairs),
//     (b) fused per-layer kernel: gather-aggregate tile -> LDS bf16 ->
//         MFMA x W -> bias/act -> store (A_hat@(H@W) == (A_hat@H)@W),
//         persistent blocks + atomic tile counter for load balance,
//     (c) 8-deep gather unroll.
// ---------------------------------------------------------------------------

using bf16x8 = __attribute__((ext_vector_type(8))) short;  // 8 bf16 = 4 VGPRs
using f32x4  = __attribute__((ext_vector_type(4))) float;

__device__ inline unsigned f2bf_bits(float f) {            // RNE f32 -> bf16
    unsigned u = __float_as_uint(f);
    return (u + 0x7fffu + ((u >> 16) & 1u)) >> 16;
}
__device__ inline float bflo(unsigned w) { return __uint_as_float(w << 16); }
__device__ inline float bfhi(unsigned w) { return __uint_as_float(w & 0xffff0000u); }

// ---------------- CSR build ----------------

__global__ void k_zero(int* __restrict__ hist, int* __restrict__ ctr, int n) {
    int i = blockIdx.x * 256 + threadIdx.x;
    if (i < n) hist[i] = 0;
    if (i < 16) ctr[i] = 0;   // work-stealing tile counters
}

__global__ void k_hist(const int* __restrict__ col, int* __restrict__ hist, int E) {
    int i = blockIdx.x * 256 + threadIdx.x;
    if (i < E) atomicAdd(&hist[col[i]], 1);
}

__global__ __launch_bounds__(256) void k_scan1(const int* __restrict__ hist,
                                               int* __restrict__ rowptr,
                                               int* __restrict__ bsum, int n) {
    __shared__ int lds[256];
    int t = threadIdx.x;
    int idx = blockIdx.x * 256 + t;
    int v = (idx < n) ? hist[idx] : 0;
    lds[t] = v; __syncthreads();
    for (int off = 1; off < 256; off <<= 1) {
        int x = (t >= off) ? lds[t - off] : 0;
        __syncthreads();
        lds[t] += x;
        __syncthreads();
    }
    if (idx < n) rowptr[idx] = lds[t] - v;
    if (t == 255) bsum[blockIdx.x] = lds[255];
}

__global__ __launch_bounds__(256) void k_scan2(const int* __restrict__ bsum,
                                               int* __restrict__ boff, int nb,
                                               int* __restrict__ rowptr, int n) {
    __shared__ int lds[256];
    int t = threadIdx.x;
    int carry = 0;
    for (int base = 0; base < nb; base += 256) {
        int v = (base + t < nb) ? bsum[base + t] : 0;
        lds[t] = v; __syncthreads();
        for (int off = 1; off < 256; off <<= 1) {
            int x = (t >= off) ? lds[t - off] : 0;
            __syncthreads();
            lds[t] += x;
            __syncthreads();
        }
        if (base + t < nb) boff[base + t] = carry + lds[t] - v;
        carry += lds[255];
        __syncthreads();
    }
    if (t == 0) rowptr[n] = carry;
}

__global__ void k_scan3(int* __restrict__ rowptr, const int* __restrict__ boff,
                        int* __restrict__ cursor, int n) {
    int i = blockIdx.x * 256 + threadIdx.x;
    if (i < n) {
        int v = rowptr[i] + boff[blockIdx.x];
        rowptr[i] = v;
        cursor[i] = v;
    }
}

// place edges col-sorted, storing {row, ew} (no dinv dependency)
__global__ void k_place(const int* __restrict__ row, const int* __restrict__ col,
                        const float* __restrict__ ew,
                        int* __restrict__ cursor, int2* __restrict__ pairs, int E) {
    int e = blockIdx.x * 256 + threadIdx.x;
    if (e >= E) return;
    int c = col[e];
    int pos = atomicAdd(&cursor[c], 1);
    pairs[pos] = make_int2(row[e], __float_as_int(ew[e]));
}

// dinv[g] = rsqrt(1 + sum ew over g's segment) — 4 lanes per node
__global__ void k_deg(const int2* __restrict__ pairs, const int* __restrict__ rowptr,
                      float* __restrict__ dinv, int n) {
    int t = blockIdx.x * 256 + threadIdx.x;
    int g = t >> 2, sub = t & 3;
    if (g >= n) return;
    int s = rowptr[g], e = rowptr[g + 1];
    float acc = 0.f;
    for (int i = s + sub; i < e; i += 4) acc += __int_as_float(pairs[i].y);
    acc += __shfl_xor(acc, 1, 4);
    acc += __shfl_xor(acc, 2, 4);
    if (sub == 0) dinv[g] = rsqrtf(1.f + acc);
}

// pairs[].y: ew -> norm = dinv[row]*ew*dinv[col]
__global__ void k_normfill(int2* __restrict__ pairs, const int* __restrict__ rowptr,
                           const float* __restrict__ dinv, int n) {
    int t = blockIdx.x * 256 + threadIdx.x;
    int g = t >> 2, sub = t & 3;
    if (g >= n) return;
    float dc = dinv[g];
    int s = rowptr[g], e = rowptr[g + 1];
    for (int i = s + sub; i < e; i += 4) {
        int2 p = pairs[i];
        float nm = dinv[p.x] * __int_as_float(p.y) * dc;
        pairs[i].y = __float_as_int(nm);
    }
}

// ---------------- input/weight prep ----------------

__global__ void k_xbf(const float* __restrict__ x, unsigned short* __restrict__ xb,
                      long total) {
    long i = (long)blockIdx.x * 256 + threadIdx.x;   // per float4
    if (i * 4 >= total) return;
    float4 v = reinterpret_cast<const float4*>(x)[i];
    ushort4 o;
    o.x = (unsigned short)f2bf_bits(v.x);
    o.y = (unsigned short)f2bf_bits(v.y);
    o.z = (unsigned short)f2bf_bits(v.z);
    o.w = (unsigned short)f2bf_bits(v.w);
    reinterpret_cast<ushort4*>(xb)[i] = o;
}

__global__ void k_wt(const float* __restrict__ W, unsigned short* __restrict__ wt,
                     int K, int N) {
    int i = blockIdx.x * 256 + threadIdx.x;
    if (i >= K * N) return;
    int k = i / N, nn = i % N;
    wt[nn * K + k] = (unsigned short)f2bf_bits(W[i]);
}

// ---------------- fused layer: T = A_hat @ Hprev ; Out = act(T @ W + b) ----
// 256 threads = 4 waves. Persistent blocks grab 128-node tiles via ctr.
// Aggregation: wave wv owns local rows [wv*32, wv*32+32); K=128: wave/node,
// K=64: 2 nodes per wave (32 lanes each). f32 acc -> bf16 -> swizzled LDS.
// MFMA phase identical to R4's verified k_gemm_mfma fragment layouts.
template <int K, int N, bool RELU, bool OUTF32>
__global__ __launch_bounds__(256) void k_layer(
    const unsigned short* __restrict__ Hprev,   // [n][K] bf16
    const unsigned short* __restrict__ Wt,      // [N][K] bf16
    const int2* __restrict__ pairs, const int* __restrict__ rowptr,
    const float* __restrict__ dinv, const float* __restrict__ bias,
    void* __restrict__ Out, int n, int ntiles, int* __restrict__ ctr)
{
    constexpr int NREP = N / 16;
    constexpr int KC   = K / 8;           // 16B chunks per row
    constexpr int KU   = K / 2;           // uints per row
    constexpr int NPW  = (K == 64) ? 2 : 1;
    __shared__ __align__(16) char Xs[128 * K * 2];
    __shared__ __align__(16) char Ws[N * K * 2];
    __shared__ int tile_s;

    const int tid  = threadIdx.x;
    const int wv   = tid >> 6;
    const int lane = tid & 63;
    const int lr   = lane & 15;
    const int lk   = lane >> 4;
    const int sub  = (NPW == 2) ? (lane >> 5) : 0;
    const int li   = (NPW == 2) ? (lane & 31) : lane;

    // stage Wt once per block (first in-loop barrier publishes it)
    for (int c = tid; c < N * KC; c += 256) {
        int r = c / KC, kc = c % KC;
        bf16x8 v = *(const bf16x8*)(Wt + (size_t)r * K + kc * 8);
        *(bf16x8*)(Ws + ((r * (K * 2) + kc * 16) ^ ((r & 7) << 4))) = v;
    }

    const unsigned* Hu = (const unsigned*)Hprev;

    for (;;) {
        __syncthreads();                  // tile_s reuse + (1st iter) Ws publish
        if (tid == 0) tile_s = atomicAdd(ctr, 1);
        __syncthreads();
        const int tile = tile_s;
        if (tile >= ntiles) break;

        // ---- aggregation into Xs ----
        const int base = tile * 128 + wv * 32;
        for (int i = 0; i < 32; i += NPW) {
            int nd = base + i + sub;
            if (nd < n) {
                int s = rowptr[nd], en = rowptr[nd + 1];
                float d = dinv[nd], d2 = d * d;
                unsigned sw = Hu[(size_t)nd * KU + li];
                float ax = d2 * bflo(sw), ay = d2 * bfhi(sw);
                int e = s;
                for (; e + 8 <= en; e += 8) {          // 8-deep gather pipeline
                    int2 pp[8]; unsigned gv[8];
                    #pragma unroll
                    for (int u = 0; u < 8; u++) pp[u] = pairs[e + u];
                    #pragma unroll
                    for (int u = 0; u < 8; u++) gv[u] = Hu[(size_t)pp[u].x * KU + li];
                    #pragma unroll
                    for (int u = 0; u < 8; u++) {
                        float nm = __int_as_float(pp[u].y);
                        ax = fmaf(nm, bflo(gv[u]), ax);
                        ay = fmaf(nm, bfhi(gv[u]), ay);
                    }
                }
                for (; e < en; e++) {
                    int2 p = pairs[e];
                    unsigned g = Hu[(size_t)p.x * KU + li];
                    float nm = __int_as_float(p.y);
                    ax = fmaf(nm, bflo(g), ax);
                    ay = fmaf(nm, bfhi(g), ay);
                }
                int rl = wv * 32 + i + sub;
                unsigned o = f2bf_bits(ax) | (f2bf_bits(ay) << 16);
                *(unsigned*)(Xs + ((rl * (K * 2) + li * 4) ^ ((rl & 7) << 4))) = o;
            }
        }
        // Xs rows are wave-private (A-frags read only own wave's rows):
        // same-wave ds_write->ds_read ordering is lgkmcnt, no barrier needed.

        // ---- MFMA: rows [wv*32, wv*32+32) x all N ----
        f32x4 acc[2][NREP];
        #pragma unroll
        for (int m = 0; m < 2; m++)
            #pragma unroll
            for (int j = 0; j < NREP; j++)
                acc[m][j] = (f32x4){0.f, 0.f, 0.f, 0.f};

        #pragma unroll
        for (int kk = 0; kk < K / 32; kk++) {
            int kc = kk * 4 + lk;
            bf16x8 af[2];
            #pragma unroll
            for (int m = 0; m < 2; m++) {
                int r = wv * 32 + m * 16 + lr;
                af[m] = *(const bf16x8*)(Xs + ((r * (K * 2) + kc * 16) ^ ((r & 7) << 4)));
            }
            #pragma unroll
            for (int j = 0; j < NREP; j++) {
                int r = j * 16 + lr;
                bf16x8 bfr = *(const bf16x8*)(Ws + ((r * (K * 2) + kc * 16) ^ ((r & 7) << 4)));
                acc[0][j] = __builtin_amdgcn_mfma_f32_16x16x32_bf16(af[0], bfr, acc[0][j], 0, 0, 0);
                acc[1][j] = __builtin_amdgcn_mfma_f32_16x16x32_bf16(af[1], bfr, acc[1][j], 0, 0, 0);
            }
        }

        // ---- epilogue: +bias, act, store ----
        #pragma unroll
        for (int m = 0; m < 2; m++) {
            #pragma unroll
            for (int j = 0; j < NREP; j++) {
                float b = bias[j * 16 + lr];
                #pragma unroll
                for (int rr = 0; rr < 4; rr++) {
                    int gr = tile * 128 + wv * 32 + m * 16 + lk * 4 + rr;
                    if (gr < n) {
                        float v = acc[m][j][rr] + b;
                        if (RELU) v = fmaxf(v, 0.f);
                        if (OUTF32)
                            ((float*)Out)[(size_t)gr * N + j * 16 + lr] = v;
                        else
                            ((unsigned short*)Out)[(size_t)gr * N + j * 16 + lr] =
                                (unsigned short)f2bf_bits(v);
                    }
                }
            }
        }
    }
}

// logits = sigmoid(dot(enc[a], enc[b])) — 16 lanes per pair, 64 channels
__global__ void k_decode(const float* __restrict__ enc, const int* __restrict__ eli,
                         int M, float* __restrict__ out)
{
    int gid  = blockIdx.x * 256 + threadIdx.x;
    int pair = gid >> 4;
    int l    = gid & 15;
    if (pair >= M) return;
    int a = eli[pair];
    int b = eli[M + pair];
    float4 va = reinterpret_cast<const float4*>(enc + (size_t)a * 64)[l];
    float4 vb = reinterpret_cast<const float4*>(enc + (size_t)b * 64)[l];
    float s = va.x * vb.x + va.y * vb.y + va.z * vb.z + va.w * vb.w;
    s += __shfl_xor(s, 8, 16);
    s += __shfl_xor(s, 4, 16);
    s += __shfl_xor(s, 2, 16);
    s += __shfl_xor(s, 1, 16);
    if (l == 0) out[pair] = 1.f / (1.f + expf(-s));
}

extern "C" void kernel_launch(void* const* d_in, const int* in_sizes, int n_in,
                              void* d_out, int out_size, void* d_ws, size_t ws_size,
                              hipStream_t stream)
{
    const float* x     = (const float*)d_in[0];
    const int*   ei    = (const int*)d_in[1];
    const float* ew    = (const float*)d_in[2];
    const int*   eli   = (const int*)d_in[3];
    const float* W_in  = (const float*)d_in[4];
    const float* b_in  = (const float*)d_in[5];
    const float* W_hid = (const float*)d_in[6];
    const float* b_hid = (const float*)d_in[7];
    const float* W_out = (const float*)d_in[8];
    const float* b_out = (const float*)d_in[9];

    const int n = in_sizes[0] / 64;
    const int E = in_sizes[1] / 2;
    const int M = in_sizes[3] / 2;
    const int* row = ei;
    const int* col = ei + E;

    const int NB     = (n + 255) / 256;
    const int nb_E   = (E + 255) / 256;
    const int ntiles = (n + 127) / 128;

    // ---- workspace layout (256B-aligned regions) ----
    char* basep = (char*)d_ws;
    size_t off = 0;
    auto alloc = [&](size_t bytes) {
        char* p = basep + off; off = (off + bytes + 255) & ~(size_t)255; return p; };
    float* dinv   = (float*)alloc((size_t)n * 4);
    int*   hist   = (int*)  alloc((size_t)n * 4);
    int*   rowptr = (int*)  alloc((size_t)(n + 1) * 4);
    int*   cursor = (int*)  alloc((size_t)n * 4);
    int*   bsum   = (int*)  alloc(1024 * 4);
    int*   boff   = (int*)  alloc(1024 * 4);
    int*   ctr    = (int*)  alloc(16 * 4);
    int2*  pairs  = (int2*) alloc((size_t)E * 8);
    unsigned short* wt_in  = (unsigned short*)alloc((size_t)128 * 64 * 2);
    unsigned short* wt_hid = (unsigned short*)alloc((size_t)4 * 128 * 128 * 2);
    unsigned short* wt_out = (unsigned short*)alloc((size_t)64 * 128 * 2);
    unsigned short* xbf    = (unsigned short*)alloc((size_t)n * 64 * 2);
    unsigned short* Hp     = (unsigned short*)alloc((size_t)n * 128 * 2);
    unsigned short* Hq     = (unsigned short*)alloc((size_t)n * 128 * 2);
    float*          enc    = (float*)alloc((size_t)n * 64 * 4);

    // ---- CSR + norm build ----
    k_zero<<<NB, 256, 0, stream>>>(hist, ctr, n);
    k_hist<<<nb_E, 256, 0, stream>>>(col, hist, E);
    k_scan1<<<NB, 256, 0, stream>>>(hist, rowptr, bsum, n);
    k_scan2<<<1, 256, 0, stream>>>(bsum, boff, NB, rowptr, n);
    k_scan3<<<NB, 256, 0, stream>>>(rowptr, boff, cursor, n);
    k_place<<<nb_E, 256, 0, stream>>>(row, col, ew, cursor, pairs, E);
    k_deg<<<(n * 4 + 255) / 256, 256, 0, stream>>>(pairs, rowptr, dinv, n);
    k_normfill<<<(n * 4 + 255) / 256, 256, 0, stream>>>(pairs, rowptr, dinv, n);

    // ---- input/weight prep ----
    k_xbf<<<(int)(((long)n * 64 / 4 + 255) / 256), 256, 0, stream>>>(x, xbf, (long)n * 64);
    k_wt<<<(64 * 128 + 255) / 256, 256, 0, stream>>>(W_in, wt_in, 64, 128);
    for (int i = 0; i < 4; i++)
        k_wt<<<(128 * 128 + 255) / 256, 256, 0, stream>>>(
            W_hid + (size_t)i * 128 * 128, wt_hid + (size_t)i * 128 * 128, 128, 128);
    k_wt<<<(128 * 64 + 255) / 256, 256, 0, stream>>>(W_out, wt_out, 128, 64);

    // ---- fused layers ----
    const int g1 = (ntiles < 1280) ? ntiles : 1280;   // 32KB LDS -> 5 blocks/CU
    const int gm = 512;                               // 64KB LDS -> 2 blocks/CU
    const int gl = (ntiles < 768) ? ntiles : 768;     // 48KB LDS -> 3 blocks/CU

    k_layer<64, 128, true, false><<<g1, 256, 0, stream>>>(
        xbf, wt_in, pairs, rowptr, dinv, b_in, Hp, n, ntiles, ctr + 0);
    k_layer<128, 128, true, false><<<gm, 256, 0, stream>>>(
        Hp, wt_hid + 0 * 16384, pairs, rowptr, dinv, b_hid + 0, Hq, n, ntiles, ctr + 1);
    k_layer<128, 128, true, false><<<gm, 256, 0, stream>>>(
        Hq, wt_hid + 1 * 16384, pairs, rowptr, dinv, b_hid + 128, Hp, n, ntiles, ctr + 2);
    k_layer<128, 128, true, false><<<gm, 256, 0, stream>>>(
        Hp, wt_hid + 2 * 16384, pairs, rowptr, dinv, b_hid + 256, Hq, n, ntiles, ctr + 3);
    k_layer<128, 128, true, false><<<gm, 256, 0, stream>>>(
        Hq, wt_hid + 3 * 16384, pairs, rowptr, dinv, b_hid + 384, Hp, n, ntiles, ctr + 4);
    k_layer<128, 64, false, true><<<gl, 256, 0, stream>>>(
        Hp, wt_out, pairs, rowptr, dinv, b_out, enc, n, ntiles, ctr + 5);

    // ---- decoder ----
    k_decode<<<(M * 16 + 255) / 256, 256, 0, stream>>>(enc, eli, M, (float*)d_out);
}

// Round 6
// 782.311 us; speedup vs baseline: 2.0809x; 2.0809x over previous
//
#include <hip/hip_runtime.h>
#include <hip/hip_bf16.h>
#include <math.h>

// ---------------------------------------------------------------------------
// GCN link-prediction encoder: 6 GCN layers + dot-product decoder.
// R6: revert R5's fusion (killed gather occupancy); R4 two-kernel structure
// (MFMA GEMM -> high-occupancy gather-aggregate) + R5's int-only CSR build
// + 8-deep gather unroll + uint-load output-layer aggregate.
// ---------------------------------------------------------------------------

using bf16x8 = __attribute__((ext_vector_type(8))) short;  // 8 bf16 = 4 VGPRs
using f32x4  = __attribute__((ext_vector_type(4))) float;

__device__ inline unsigned f2bf_bits(float f) {            // RNE f32 -> bf16
    unsigned u = __float_as_uint(f);
    return (u + 0x7fffu + ((u >> 16) & 1u)) >> 16;
}
__device__ inline float bflo(unsigned w) { return __uint_as_float(w << 16); }
__device__ inline float bfhi(unsigned w) { return __uint_as_float(w & 0xffff0000u); }

// ---------------- CSR build (int-only atomics) ----------------

__global__ void k_zero(int* __restrict__ hist, int n) {
    int i = blockIdx.x * 256 + threadIdx.x;
    if (i < n) hist[i] = 0;
}

__global__ void k_hist(const int* __restrict__ col, int* __restrict__ hist, int E) {
    int i = blockIdx.x * 256 + threadIdx.x;
    if (i < E) atomicAdd(&hist[col[i]], 1);
}

__global__ __launch_bounds__(256) void k_scan1(const int* __restrict__ hist,
                                               int* __restrict__ rowptr,
                                               int* __restrict__ bsum, int n) {
    __shared__ int lds[256];
    int t = threadIdx.x;
    int idx = blockIdx.x * 256 + t;
    int v = (idx < n) ? hist[idx] : 0;
    lds[t] = v; __syncthreads();
    for (int off = 1; off < 256; off <<= 1) {
        int x = (t >= off) ? lds[t - off] : 0;
        __syncthreads();
        lds[t] += x;
        __syncthreads();
    }
    if (idx < n) rowptr[idx] = lds[t] - v;
    if (t == 255) bsum[blockIdx.x] = lds[255];
}

__global__ __launch_bounds__(256) void k_scan2(const int* __restrict__ bsum,
                                               int* __restrict__ boff, int nb,
                                               int* __restrict__ rowptr, int n) {
    __shared__ int lds[256];
    int t = threadIdx.x;
    int carry = 0;
    for (int base = 0; base < nb; base += 256) {
        int v = (base + t < nb) ? bsum[base + t] : 0;
        lds[t] = v; __syncthreads();
        for (int off = 1; off < 256; off <<= 1) {
            int x = (t >= off) ? lds[t - off] : 0;
            __syncthreads();
            lds[t] += x;
            __syncthreads();
        }
        if (base + t < nb) boff[base + t] = carry + lds[t] - v;
        carry += lds[255];
        __syncthreads();
    }
    if (t == 0) rowptr[n] = carry;
}

__global__ void k_scan3(int* __restrict__ rowptr, const int* __restrict__ boff,
                        int* __restrict__ cursor, int n) {
    int i = blockIdx.x * 256 + threadIdx.x;
    if (i < n) {
        int v = rowptr[i] + boff[blockIdx.x];
        rowptr[i] = v;
        cursor[i] = v;
    }
}

// place edges col-sorted, storing {row, ew} (no dinv dependency)
__global__ void k_place(const int* __restrict__ row, const int* __restrict__ col,
                        const float* __restrict__ ew,
                        int* __restrict__ cursor, int2* __restrict__ pairs, int E) {
    int e = blockIdx.x * 256 + threadIdx.x;
    if (e >= E) return;
    int c = col[e];
    int pos = atomicAdd(&cursor[c], 1);
    pairs[pos] = make_int2(row[e], __float_as_int(ew[e]));
}

// dinv[g] = rsqrt(1 + sum ew over g's segment) — 4 lanes per node
__global__ void k_deg(const int2* __restrict__ pairs, const int* __restrict__ rowptr,
                      float* __restrict__ dinv, int n) {
    int t = blockIdx.x * 256 + threadIdx.x;
    int g = t >> 2, sub = t & 3;
    if (g >= n) return;
    int s = rowptr[g], e = rowptr[g + 1];
    float acc = 0.f;
    for (int i = s + sub; i < e; i += 4) acc += __int_as_float(pairs[i].y);
    acc += __shfl_xor(acc, 1, 4);
    acc += __shfl_xor(acc, 2, 4);
    if (sub == 0) dinv[g] = rsqrtf(1.f + acc);
}

// pairs[].y: ew -> norm = dinv[row]*ew*dinv[col]
__global__ void k_normfill(int2* __restrict__ pairs, const int* __restrict__ rowptr,
                           const float* __restrict__ dinv, int n) {
    int t = blockIdx.x * 256 + threadIdx.x;
    int g = t >> 2, sub = t & 3;
    if (g >= n) return;
    float dc = dinv[g];
    int s = rowptr[g], e = rowptr[g + 1];
    for (int i = s + sub; i < e; i += 4) {
        int2 p = pairs[i];
        float nm = dinv[p.x] * __int_as_float(p.y) * dc;
        pairs[i].y = __float_as_int(nm);
    }
}

// ---------------- weight prep: W[K][N] f32 -> Wt[N][K] bf16 ----------------

__global__ void k_wt(const float* __restrict__ W, unsigned short* __restrict__ wt,
                     int K, int N) {
    int i = blockIdx.x * 256 + threadIdx.x;
    if (i >= K * N) return;
    int k = i / N, nn = i % N;
    wt[nn * K + k] = (unsigned short)f2bf_bits(W[i]);
}

// ---------------- MFMA GEMM: H = X @ W, bf16 in, f32 acc, bf16 out --------
// 128-row tile, 256 threads = 4 waves, wave w does rows [w*32, w*32+32).
// X and Wt staged in LDS (bf16, XOR-swizzled: byte ^= (row&7)<<4).
template <int K, int N, bool IN_BF16>
__global__ __launch_bounds__(256, 2) void k_gemm_mfma(
    const void* __restrict__ Xv, const unsigned short* __restrict__ Wt,
    unsigned short* __restrict__ H, int n)
{
    constexpr int NREP = N / 16;
    constexpr int KC   = K / 8;          // 16B chunks per row
    __shared__ char lds[128 * K * 2 + N * K * 2];
    char* Xs = lds;
    char* Ws = lds + 128 * K * 2;

    const int row0 = blockIdx.x * 128;
    const int tid  = threadIdx.x;

    for (int c = tid; c < 128 * KC; c += 256) {
        int r = c / KC, kc = c % KC;
        int gr = row0 + r;
        bf16x8 v = {0, 0, 0, 0, 0, 0, 0, 0};
        if (gr < n) {
            if constexpr (IN_BF16) {
                v = *(const bf16x8*)((const unsigned short*)Xv + (size_t)gr * K + kc * 8);
            } else {
                const float* xp = (const float*)Xv + (size_t)gr * K + kc * 8;
                float4 a = *(const float4*)xp;
                float4 b = *(const float4*)(xp + 4);
                v[0] = (short)f2bf_bits(a.x); v[1] = (short)f2bf_bits(a.y);
                v[2] = (short)f2bf_bits(a.z); v[3] = (short)f2bf_bits(a.w);
                v[4] = (short)f2bf_bits(b.x); v[5] = (short)f2bf_bits(b.y);
                v[6] = (short)f2bf_bits(b.z); v[7] = (short)f2bf_bits(b.w);
            }
        }
        *(bf16x8*)(Xs + ((r * (K * 2) + kc * 16) ^ ((r & 7) << 4))) = v;
    }
    for (int c = tid; c < N * KC; c += 256) {
        int r = c / KC, kc = c % KC;
        bf16x8 v = *(const bf16x8*)(Wt + (size_t)r * K + kc * 8);
        *(bf16x8*)(Ws + ((r * (K * 2) + kc * 16) ^ ((r & 7) << 4))) = v;
    }
    __syncthreads();

    const int wv   = tid >> 6;
    const int lane = tid & 63;
    const int lr   = lane & 15;
    const int lk   = lane >> 4;

    f32x4 acc[2][NREP];
    #pragma unroll
    for (int m = 0; m < 2; m++)
        #pragma unroll
        for (int j = 0; j < NREP; j++)
            acc[m][j] = (f32x4){0.f, 0.f, 0.f, 0.f};

    #pragma unroll
    for (int kk = 0; kk < K / 32; kk++) {
        int kc = kk * 4 + lk;
        bf16x8 af[2];
        #pragma unroll
        for (int m = 0; m < 2; m++) {
            int r = wv * 32 + m * 16 + lr;
            af[m] = *(const bf16x8*)(Xs + ((r * (K * 2) + kc * 16) ^ ((r & 7) << 4)));
        }
        #pragma unroll
        for (int j = 0; j < NREP; j++) {
            int r = j * 16 + lr;
            bf16x8 bfr = *(const bf16x8*)(Ws + ((r * (K * 2) + kc * 16) ^ ((r & 7) << 4)));
            acc[0][j] = __builtin_amdgcn_mfma_f32_16x16x32_bf16(af[0], bfr, acc[0][j], 0, 0, 0);
            acc[1][j] = __builtin_amdgcn_mfma_f32_16x16x32_bf16(af[1], bfr, acc[1][j], 0, 0, 0);
        }
    }

    #pragma unroll
    for (int m = 0; m < 2; m++) {
        #pragma unroll
        for (int j = 0; j < NREP; j++) {
            #pragma unroll
            for (int rr = 0; rr < 4; rr++) {
                int gr = row0 + wv * 32 + m * 16 + lk * 4 + rr;
                if (gr < n)
                    H[(size_t)gr * N + j * 16 + lr] = (unsigned short)f2bf_bits(acc[m][j][rr]);
            }
        }
    }
}

// ---------------- gather-aggregate (OC=128): fused selfloop+bias+relu -----
// Out[c] = act( dinv[c]^2*H[c] + sum_e norm[e]*H[row[e]] + bias )
// one wave per node; 64 lanes x uint (2 bf16 ch each). 8-deep unroll.
template <bool RELU>
__global__ __launch_bounds__(256) void k_aggregate128(
    const unsigned short* __restrict__ H, const int2* __restrict__ pairs,
    const int* __restrict__ rowptr, const float* __restrict__ dinv,
    const float* __restrict__ bias, unsigned* __restrict__ Out, int n)
{
    const int lane = threadIdx.x & 63;
    const int w    = threadIdx.x >> 6;
    int nd = blockIdx.x * 4 + w;
    if (nd >= n) return;
    int s  = rowptr[nd];
    int en = rowptr[nd + 1];
    float d  = dinv[nd];
    float d2 = d * d;

    const unsigned* Hu = (const unsigned*)H;
    unsigned sw = Hu[(size_t)nd * 64 + lane];
    float ax = d2 * bflo(sw), ay = d2 * bfhi(sw);
    int e = s;
    for (; e + 8 <= en; e += 8) {               // 8-deep gather pipeline
        int2 pp[8]; unsigned gv[8];
        #pragma unroll
        for (int u = 0; u < 8; u++) pp[u] = pairs[e + u];
        #pragma unroll
        for (int u = 0; u < 8; u++) gv[u] = Hu[(size_t)pp[u].x * 64 + lane];
        #pragma unroll
        for (int u = 0; u < 8; u++) {
            float nm = __int_as_float(pp[u].y);
            ax = fmaf(nm, bflo(gv[u]), ax);
            ay = fmaf(nm, bfhi(gv[u]), ay);
        }
    }
    for (; e < en; e++) {
        int2 p = pairs[e];
        unsigned g = Hu[(size_t)p.x * 64 + lane];
        float nm = __int_as_float(p.y);
        ax = fmaf(nm, bflo(g), ax);
        ay = fmaf(nm, bfhi(g), ay);
    }
    float2 bb = reinterpret_cast<const float2*>(bias)[lane];
    ax += bb.x; ay += bb.y;
    if (RELU) { ax = fmaxf(ax, 0.f); ay = fmaxf(ay, 0.f); }
    Out[(size_t)nd * 64 + lane] = f2bf_bits(ax) | (f2bf_bits(ay) << 16);
}

// ---------------- gather-aggregate (OC=64, f32 out): 2 nodes per wave -----
__global__ __launch_bounds__(256) void k_aggregate64(
    const unsigned short* __restrict__ H, const int2* __restrict__ pairs,
    const int* __restrict__ rowptr, const float* __restrict__ dinv,
    const float* __restrict__ bias, float2* __restrict__ Out, int n)
{
    const int lane = threadIdx.x & 63;
    const int w    = threadIdx.x >> 6;
    const int li   = lane & 31;                 // uint index within row (32*4B=128B)
    int nd = (blockIdx.x * 4 + w) * 2 + (lane >> 5);
    if (nd >= n) return;
    int s  = rowptr[nd];
    int en = rowptr[nd + 1];
    float d  = dinv[nd];
    float d2 = d * d;

    const unsigned* Hu = (const unsigned*)H;    // 32 uints per row
    unsigned sw = Hu[(size_t)nd * 32 + li];
    float ax = d2 * bflo(sw), ay = d2 * bfhi(sw);
    int e = s;
    for (; e + 8 <= en; e += 8) {
        int2 pp[8]; unsigned gv[8];
        #pragma unroll
        for (int u = 0; u < 8; u++) pp[u] = pairs[e + u];
        #pragma unroll
        for (int u = 0; u < 8; u++) gv[u] = Hu[(size_t)pp[u].x * 32 + li];
        #pragma unroll
        for (int u = 0; u < 8; u++) {
            float nm = __int_as_float(pp[u].y);
            ax = fmaf(nm, bflo(gv[u]), ax);
            ay = fmaf(nm, bfhi(gv[u]), ay);
        }
    }
    for (; e < en; e++) {
        int2 p = pairs[e];
        unsigned g = Hu[(size_t)p.x * 32 + li];
        float nm = __int_as_float(p.y);
        ax = fmaf(nm, bflo(g), ax);
        ay = fmaf(nm, bfhi(g), ay);
    }
    float2 bb = reinterpret_cast<const float2*>(bias)[li];
    ax += bb.x; ay += bb.y;
    Out[(size_t)nd * 32 + li] = make_float2(ax, ay);   // enc stays f32
}

// logits = sigmoid(dot(enc[a], enc[b])) — 16 lanes per pair, 64 channels
__global__ void k_decode(const float* __restrict__ enc, const int* __restrict__ eli,
                         int M, float* __restrict__ out)
{
    int gid  = blockIdx.x * 256 + threadIdx.x;
    int pair = gid >> 4;
    int l    = gid & 15;
    if (pair >= M) return;
    int a = eli[pair];
    int b = eli[M + pair];
    float4 va = reinterpret_cast<const float4*>(enc + (size_t)a * 64)[l];
    float4 vb = reinterpret_cast<const float4*>(enc + (size_t)b * 64)[l];
    float s = va.x * vb.x + va.y * vb.y + va.z * vb.z + va.w * vb.w;
    s += __shfl_xor(s, 8, 16);
    s += __shfl_xor(s, 4, 16);
    s += __shfl_xor(s, 2, 16);
    s += __shfl_xor(s, 1, 16);
    if (l == 0) out[pair] = 1.f / (1.f + expf(-s));
}

extern "C" void kernel_launch(void* const* d_in, const int* in_sizes, int n_in,
                              void* d_out, int out_size, void* d_ws, size_t ws_size,
                              hipStream_t stream)
{
    const float* x     = (const float*)d_in[0];
    const int*   ei    = (const int*)d_in[1];
    const float* ew    = (const float*)d_in[2];
    const int*   eli   = (const int*)d_in[3];
    const float* W_in  = (const float*)d_in[4];
    const float* b_in  = (const float*)d_in[5];
    const float* W_hid = (const float*)d_in[6];
    const float* b_hid = (const float*)d_in[7];
    const float* W_out = (const float*)d_in[8];
    const float* b_out = (const float*)d_in[9];

    const int n = in_sizes[0] / 64;
    const int E = in_sizes[1] / 2;
    const int M = in_sizes[3] / 2;
    const int* row = ei;
    const int* col = ei + E;

    const int NB   = (n + 255) / 256;
    const int nb_E = (E + 255) / 256;
    const int gb   = (n + 127) / 128;
    const int ab   = (n + 3) / 4;

    // ---- workspace layout (256B-aligned regions) ----
    char* basep = (char*)d_ws;
    size_t off = 0;
    auto alloc = [&](size_t bytes) {
        char* p = basep + off; off = (off + bytes + 255) & ~(size_t)255; return p; };
    float* dinv   = (float*)alloc((size_t)n * 4);
    int*   hist   = (int*)  alloc((size_t)n * 4);
    int*   rowptr = (int*)  alloc((size_t)(n + 1) * 4);
    int*   cursor = (int*)  alloc((size_t)n * 4);
    int*   bsum   = (int*)  alloc(1024 * 4);
    int*   boff   = (int*)  alloc(1024 * 4);
    int2*  pairs  = (int2*) alloc((size_t)E * 8);
    unsigned short* wt_in  = (unsigned short*)alloc((size_t)128 * 64 * 2);
    unsigned short* wt_hid = (unsigned short*)alloc((size_t)4 * 128 * 128 * 2);
    unsigned short* wt_out = (unsigned short*)alloc((size_t)64 * 128 * 2);
    unsigned short* Hbf    = (unsigned short*)alloc((size_t)n * 128 * 2);  // GEMM out
    unsigned short* Abf    = (unsigned short*)alloc((size_t)n * 128 * 2);  // activations
    float*          enc    = (float*)alloc((size_t)n * 64 * 4);

    // ---- CSR + norm build (int-only atomics) ----
    k_zero<<<NB, 256, 0, stream>>>(hist, n);
    k_hist<<<nb_E, 256, 0, stream>>>(col, hist, E);
    k_scan1<<<NB, 256, 0, stream>>>(hist, rowptr, bsum, n);
    k_scan2<<<1, 256, 0, stream>>>(bsum, boff, NB, rowptr, n);
    k_scan3<<<NB, 256, 0, stream>>>(rowptr, boff, cursor, n);
    k_place<<<nb_E, 256, 0, stream>>>(row, col, ew, cursor, pairs, E);
    k_deg<<<(n * 4 + 255) / 256, 256, 0, stream>>>(pairs, rowptr, dinv, n);
    k_normfill<<<(n * 4 + 255) / 256, 256, 0, stream>>>(pairs, rowptr, dinv, n);

    // ---- weight prep (f32 -> bf16, transposed [N][K]) ----
    k_wt<<<(64 * 128 + 255) / 256, 256, 0, stream>>>(W_in, wt_in, 64, 128);
    for (int i = 0; i < 4; i++)
        k_wt<<<(128 * 128 + 255) / 256, 256, 0, stream>>>(
            W_hid + (size_t)i * 128 * 128, wt_hid + (size_t)i * 128 * 128, 128, 128);
    k_wt<<<(128 * 64 + 255) / 256, 256, 0, stream>>>(W_out, wt_out, 128, 64);

    // ---- layer 1: 64 -> 128 (x f32 in, converted in GEMM staging) ----
    k_gemm_mfma<64, 128, false><<<gb, 256, 0, stream>>>(x, wt_in, Hbf, n);
    k_aggregate128<true><<<ab, 256, 0, stream>>>(Hbf, pairs, rowptr, dinv, b_in,
                                                 (unsigned*)Abf, n);

    // ---- 4 hidden layers: 128 -> 128 ----
    for (int i = 0; i < 4; i++) {
        k_gemm_mfma<128, 128, true><<<gb, 256, 0, stream>>>(
            Abf, wt_hid + (size_t)i * 128 * 128, Hbf, n);
        k_aggregate128<true><<<ab, 256, 0, stream>>>(
            Hbf, pairs, rowptr, dinv, b_hid + (size_t)i * 128, (unsigned*)Abf, n);
    }

    // ---- output layer: 128 -> 64 ----
    k_gemm_mfma<128, 64, true><<<gb, 256, 0, stream>>>(Abf, wt_out, Hbf, n);
    k_aggregate64<<<(n + 7) / 8, 256, 0, stream>>>(Hbf, pairs, rowptr, dinv, b_out,
                                                   (float2*)enc, n);

    // ---- decoder ----
    k_decode<<<(M * 16 + 255) / 256, 256, 0, stream>>>(enc, eli, M, (float*)d_out);
}

// Round 9
// 763.698 us; speedup vs baseline: 2.1316x; 1.0244x over previous
//
#include <hip/hip_runtime.h>
#include <hip/hip_bf16.h>
#include <math.h>

// ---------------------------------------------------------------------------
// GCN link-prediction encoder: 6 GCN layers + dot-product decoder.
// R7 (on R6 base): (1) norm computed on-the-fly in aggregates (dinv[row] is
// an L2-resident broadcast load) -> k_normfill deleted; (2) enc stored bf16
// -> decoder's 205 MB random gather halves.
// ---------------------------------------------------------------------------

using bf16x8 = __attribute__((ext_vector_type(8))) short;  // 8 bf16 = 4 VGPRs
using f32x4  = __attribute__((ext_vector_type(4))) float;

__device__ inline unsigned f2bf_bits(float f) {            // RNE f32 -> bf16
    unsigned u = __float_as_uint(f);
    return (u + 0x7fffu + ((u >> 16) & 1u)) >> 16;
}
__device__ inline float bflo(unsigned w) { return __uint_as_float(w << 16); }
__device__ inline float bfhi(unsigned w) { return __uint_as_float(w & 0xffff0000u); }

// ---------------- CSR build (int-only atomics) ----------------

__global__ void k_zero(int* __restrict__ hist, int n) {
    int i = blockIdx.x * 256 + threadIdx.x;
    if (i < n) hist[i] = 0;
}

__global__ void k_hist(const int* __restrict__ col, int* __restrict__ hist, int E) {
    int i = blockIdx.x * 256 + threadIdx.x;
    if (i < E) atomicAdd(&hist[col[i]], 1);
}

__global__ __launch_bounds__(256) void k_scan1(const int* __restrict__ hist,
                                               int* __restrict__ rowptr,
                                               int* __restrict__ bsum, int n) {
    __shared__ int lds[256];
    int t = threadIdx.x;
    int idx = blockIdx.x * 256 + t;
    int v = (idx < n) ? hist[idx] : 0;
    lds[t] = v; __syncthreads();
    for (int off = 1; off < 256; off <<= 1) {
        int x = (t >= off) ? lds[t - off] : 0;
        __syncthreads();
        lds[t] += x;
        __syncthreads();
    }
    if (idx < n) rowptr[idx] = lds[t] - v;
    if (t == 255) bsum[blockIdx.x] = lds[255];
}

__global__ __launch_bounds__(256) void k_scan2(const int* __restrict__ bsum,
                                               int* __restrict__ boff, int nb,
                                               int* __restrict__ rowptr, int n) {
    __shared__ int lds[256];
    int t = threadIdx.x;
    int carry = 0;
    for (int base = 0; base < nb; base += 256) {
        int v = (base + t < nb) ? bsum[base + t] : 0;
        lds[t] = v; __syncthreads();
        for (int off = 1; off < 256; off <<= 1) {
            int x = (t >= off) ? lds[t - off] : 0;
            __syncthreads();
            lds[t] += x;
            __syncthreads();
        }
        if (base + t < nb) boff[base + t] = carry + lds[t] - v;
        carry += lds[255];
        __syncthreads();
    }
    if (t == 0) rowptr[n] = carry;
}

__global__ void k_scan3(int* __restrict__ rowptr, const int* __restrict__ boff,
                        int* __restrict__ cursor, int n) {
    int i = blockIdx.x * 256 + threadIdx.x;
    if (i < n) {
        int v = rowptr[i] + boff[blockIdx.x];
        rowptr[i] = v;
        cursor[i] = v;
    }
}

// place edges col-sorted, storing {row, ew}
__global__ void k_place(const int* __restrict__ row, const int* __restrict__ col,
                        const float* __restrict__ ew,
                        int* __restrict__ cursor, int2* __restrict__ pairs, int E) {
    int e = blockIdx.x * 256 + threadIdx.x;
    if (e >= E) return;
    int c = col[e];
    int pos = atomicAdd(&cursor[c], 1);
    pairs[pos] = make_int2(row[e], __float_as_int(ew[e]));
}

// dinv[g] = rsqrt(1 + sum ew over g's segment) — 4 lanes per node
__global__ void k_deg(const int2* __restrict__ pairs, const int* __restrict__ rowptr,
                      float* __restrict__ dinv, int n) {
    int t = blockIdx.x * 256 + threadIdx.x;
    int g = t >> 2, sub = t & 3;
    if (g >= n) return;
    int s = rowptr[g], e = rowptr[g + 1];
    float acc = 0.f;
    for (int i = s + sub; i < e; i += 4) acc += __int_as_float(pairs[i].y);
    acc += __shfl_xor(acc, 1, 4);
    acc += __shfl_xor(acc, 2, 4);
    if (sub == 0) dinv[g] = rsqrtf(1.f + acc);
}

// ---------------- weight prep: W[K][N] f32 -> Wt[N][K] bf16 ----------------

__global__ void k_wt(const float* __restrict__ W, unsigned short* __restrict__ wt,
                     int K, int N) {
    int i = blockIdx.x * 256 + threadIdx.x;
    if (i >= K * N) return;
    int k = i / N, nn = i % N;
    wt[nn * K + k] = (unsigned short)f2bf_bits(W[i]);
}

// ---------------- MFMA GEMM: H = X @ W, bf16 in, f32 acc, bf16 out --------
// 128-row tile, 256 threads = 4 waves, wave w does rows [w*32, w*32+32).
// X and Wt staged in LDS (bf16, XOR-swizzled: byte ^= (row&7)<<4).
template <int K, int N, bool IN_BF16>
__global__ __launch_bounds__(256, 2) void k_gemm_mfma(
    const void* __restrict__ Xv, const unsigned short* __restrict__ Wt,
    unsigned short* __restrict__ H, int n)
{
    constexpr int NREP = N / 16;
    constexpr int KC   = K / 8;          // 16B chunks per row
    __shared__ char lds[128 * K * 2 + N * K * 2];
    char* Xs = lds;
    char* Ws = lds + 128 * K * 2;

    const int row0 = blockIdx.x * 128;
    const int tid  = threadIdx.x;

    for (int c = tid; c < 128 * KC; c += 256) {
        int r = c / KC, kc = c % KC;
        int gr = row0 + r;
        bf16x8 v = {0, 0, 0, 0, 0, 0, 0, 0};
        if (gr < n) {
            if constexpr (IN_BF16) {
                v = *(const bf16x8*)((const unsigned short*)Xv + (size_t)gr * K + kc * 8);
            } else {
                const float* xp = (const float*)Xv + (size_t)gr * K + kc * 8;
                float4 a = *(const float4*)xp;
                float4 b = *(const float4*)(xp + 4);
                v[0] = (short)f2bf_bits(a.x); v[1] = (short)f2bf_bits(a.y);
                v[2] = (short)f2bf_bits(a.z); v[3] = (short)f2bf_bits(a.w);
                v[4] = (short)f2bf_bits(b.x); v[5] = (short)f2bf_bits(b.y);
                v[6] = (short)f2bf_bits(b.z); v[7] = (short)f2bf_bits(b.w);
            }
        }
        *(bf16x8*)(Xs + ((r * (K * 2) + kc * 16) ^ ((r & 7) << 4))) = v;
    }
    for (int c = tid; c < N * KC; c += 256) {
        int r = c / KC, kc = c % KC;
        bf16x8 v = *(const bf16x8*)(Wt + (size_t)r * K + kc * 8);
        *(bf16x8*)(Ws + ((r * (K * 2) + kc * 16) ^ ((r & 7) << 4))) = v;
    }
    __syncthreads();

    const int wv   = tid >> 6;
    const int lane = tid & 63;
    const int lr   = lane & 15;
    const int lk   = lane >> 4;

    f32x4 acc[2][NREP];
    #pragma unroll
    for (int m = 0; m < 2; m++)
        #pragma unroll
        for (int j = 0; j < NREP; j++)
            acc[m][j] = (f32x4){0.f, 0.f, 0.f, 0.f};

    #pragma unroll
    for (int kk = 0; kk < K / 32; kk++) {
        int kc = kk * 4 + lk;
        bf16x8 af[2];
        #pragma unroll
        for (int m = 0; m < 2; m++) {
            int r = wv * 32 + m * 16 + lr;
            af[m] = *(const bf16x8*)(Xs + ((r * (K * 2) + kc * 16) ^ ((r & 7) << 4)));
        }
        #pragma unroll
        for (int j = 0; j < NREP; j++) {
            int r = j * 16 + lr;
            bf16x8 bfr = *(const bf16x8*)(Ws + ((r * (K * 2) + kc * 16) ^ ((r & 7) << 4)));
            acc[0][j] = __builtin_amdgcn_mfma_f32_16x16x32_bf16(af[0], bfr, acc[0][j], 0, 0, 0);
            acc[1][j] = __builtin_amdgcn_mfma_f32_16x16x32_bf16(af[1], bfr, acc[1][j], 0, 0, 0);
        }
    }

    #pragma unroll
    for (int m = 0; m < 2; m++) {
        #pragma unroll
        for (int j = 0; j < NREP; j++) {
            #pragma unroll
            for (int rr = 0; rr < 4; rr++) {
                int gr = row0 + wv * 32 + m * 16 + lk * 4 + rr;
                if (gr < n)
                    H[(size_t)gr * N + j * 16 + lr] = (unsigned short)f2bf_bits(acc[m][j][rr]);
            }
        }
    }
}

// ---------------- gather-aggregate (OC=128): on-the-fly norm --------------
// Out[c] = act( dinv[c]^2*H[c] + sum_e dinv[row]*ew*dinv[c]*H[row[e]] + b )
// one wave per node; pairs/dinv loads are wave-uniform broadcasts.
template <bool RELU>
__global__ __launch_bounds__(256) void k_aggregate128(
    const unsigned short* __restrict__ H, const int2* __restrict__ pairs,
    const int* __restrict__ rowptr, const float* __restrict__ dinv,
    const float* __restrict__ bias, unsigned* __restrict__ Out, int n)
{
    const int lane = threadIdx.x & 63;
    const int w    = threadIdx.x >> 6;
    int nd = blockIdx.x * 4 + w;
    if (nd >= n) return;
    int s  = rowptr[nd];
    int en = rowptr[nd + 1];
    float d  = dinv[nd];
    float d2 = d * d;

    const unsigned* Hu = (const unsigned*)H;
    unsigned sw = Hu[(size_t)nd * 64 + lane];
    float ax = d2 * bflo(sw), ay = d2 * bfhi(sw);
    int e = s;
    for (; e + 8 <= en; e += 8) {               // 8-deep gather pipeline
        int2 pp[8]; float dv[8]; unsigned gv[8];
        #pragma unroll
        for (int u = 0; u < 8; u++) pp[u] = pairs[e + u];
        #pragma unroll
        for (int u = 0; u < 8; u++) dv[u] = dinv[pp[u].x];
        #pragma unroll
        for (int u = 0; u < 8; u++) gv[u] = Hu[(size_t)pp[u].x * 64 + lane];
        #pragma unroll
        for (int u = 0; u < 8; u++) {
            float nm = dv[u] * __int_as_float(pp[u].y) * d;
            ax = fmaf(nm, bflo(gv[u]), ax);
            ay = fmaf(nm, bfhi(gv[u]), ay);
        }
    }
    for (; e < en; e++) {
        int2 p = pairs[e];
        float nm = dinv[p.x] * __int_as_float(p.y) * d;
        unsigned g = Hu[(size_t)p.x * 64 + lane];
        ax = fmaf(nm, bflo(g), ax);
        ay = fmaf(nm, bfhi(g), ay);
    }
    float2 bb = reinterpret_cast<const float2*>(bias)[lane];
    ax += bb.x; ay += bb.y;
    if (RELU) { ax = fmaxf(ax, 0.f); ay = fmaxf(ay, 0.f); }
    Out[(size_t)nd * 64 + lane] = f2bf_bits(ax) | (f2bf_bits(ay) << 16);
}

// ---------------- gather-aggregate (OC=64, bf16 out): 2 nodes per wave ----
__global__ __launch_bounds__(256) void k_aggregate64(
    const unsigned short* __restrict__ H, const int2* __restrict__ pairs,
    const int* __restrict__ rowptr, const float* __restrict__ dinv,
    const float* __restrict__ bias, unsigned* __restrict__ Out, int n)
{
    const int lane = threadIdx.x & 63;
    const int w    = threadIdx.x >> 6;
    const int li   = lane & 31;                 // uint index within row (32*4B=128B)
    int nd = (blockIdx.x * 4 + w) * 2 + (lane >> 5);
    if (nd >= n) return;
    int s  = rowptr[nd];
    int en = rowptr[nd + 1];
    float d  = dinv[nd];
    float d2 = d * d;

    const unsigned* Hu = (const unsigned*)H;    // 32 uints per row
    unsigned sw = Hu[(size_t)nd * 32 + li];
    float ax = d2 * bflo(sw), ay = d2 * bfhi(sw);
    int e = s;
    for (; e + 8 <= en; e += 8) {
        int2 pp[8]; float dv[8]; unsigned gv[8];
        #pragma unroll
        for (int u = 0; u < 8; u++) pp[u] = pairs[e + u];
        #pragma unroll
        for (int u = 0; u < 8; u++) dv[u] = dinv[pp[u].x];
        #pragma unroll
        for (int u = 0; u < 8; u++) gv[u] = Hu[(size_t)pp[u].x * 32 + li];
        #pragma unroll
        for (int u = 0; u < 8; u++) {
            float nm = dv[u] * __int_as_float(pp[u].y) * d;
            ax = fmaf(nm, bflo(gv[u]), ax);
            ay = fmaf(nm, bfhi(gv[u]), ay);
        }
    }
    for (; e < en; e++) {
        int2 p = pairs[e];
        float nm = dinv[p.x] * __int_as_float(p.y) * d;
        unsigned g = Hu[(size_t)p.x * 32 + li];
        ax = fmaf(nm, bflo(g), ax);
        ay = fmaf(nm, bfhi(g), ay);
    }
    float2 bb = reinterpret_cast<const float2*>(bias)[li];
    ax += bb.x; ay += bb.y;
    Out[(size_t)nd * 32 + li] = f2bf_bits(ax) | (f2bf_bits(ay) << 16);  // enc bf16
}

// logits = sigmoid(dot(enc[a], enc[b])) — 8 lanes/pair, bf16 enc (128B rows)
__global__ void k_decode(const unsigned short* __restrict__ enc,
                         const int* __restrict__ eli, int M, float* __restrict__ out)
{
    int gid  = blockIdx.x * 256 + threadIdx.x;
    int pair = gid >> 3;
    int l    = gid & 7;
    if (pair >= M) return;
    int a = eli[pair];
    int b = eli[M + pair];
    const uint4* E4 = (const uint4*)enc;        // 8 uint4 per 64-ch row
    uint4 va = E4[(size_t)a * 8 + l];
    uint4 vb = E4[(size_t)b * 8 + l];
    float s = 0.f;
    s = fmaf(bflo(va.x), bflo(vb.x), s); s = fmaf(bfhi(va.x), bfhi(vb.x), s);
    s = fmaf(bflo(va.y), bflo(vb.y), s); s = fmaf(bfhi(va.y), bfhi(vb.y), s);
    s = fmaf(bflo(va.z), bflo(vb.z), s); s = fmaf(bfhi(va.z), bfhi(vb.z), s);
    s = fmaf(bflo(va.w), bflo(vb.w), s); s = fmaf(bfhi(va.w), bfhi(vb.w), s);
    s += __shfl_xor(s, 4, 8);
    s += __shfl_xor(s, 2, 8);
    s += __shfl_xor(s, 1, 8);
    if (l == 0) out[pair] = 1.f / (1.f + expf(-s));
}

extern "C" void kernel_launch(void* const* d_in, const int* in_sizes, int n_in,
                              void* d_out, int out_size, void* d_ws, size_t ws_size,
                              hipStream_t stream)
{
    const float* x     = (const float*)d_in[0];
    const int*   ei    = (const int*)d_in[1];
    const float* ew    = (const float*)d_in[2];
    const int*   eli   = (const int*)d_in[3];
    const float* W_in  = (const float*)d_in[4];
    const float* b_in  = (const float*)d_in[5];
    const float* W_hid = (const float*)d_in[6];
    const float* b_hid = (const float*)d_in[7];
    const float* W_out = (const float*)d_in[8];
    const float* b_out = (const float*)d_in[9];

    const int n = in_sizes[0] / 64;
    const int E = in_sizes[1] / 2;
    const int M = in_sizes[3] / 2;
    const int* row = ei;
    const int* col = ei + E;

    const int NB   = (n + 255) / 256;
    const int nb_E = (E + 255) / 256;
    const int gb   = (n + 127) / 128;
    const int ab   = (n + 3) / 4;

    // ---- workspace layout (256B-aligned regions) ----
    char* basep = (char*)d_ws;
    size_t off = 0;
    auto alloc = [&](size_t bytes) {
        char* p = basep + off; off = (off + bytes + 255) & ~(size_t)255; return p; };
    float* dinv   = (float*)alloc((size_t)n * 4);
    int*   hist   = (int*)  alloc((size_t)n * 4);
    int*   rowptr = (int*)  alloc((size_t)(n + 1) * 4);
    int*   cursor = (int*)  alloc((size_t)n * 4);
    int*   bsum   = (int*)  alloc(1024 * 4);
    int*   boff   = (int*)  alloc(1024 * 4);
    int2*  pairs  = (int2*) alloc((size_t)E * 8);
    unsigned short* wt_in  = (unsigned short*)alloc((size_t)128 * 64 * 2);
    unsigned short* wt_hid = (unsigned short*)alloc((size_t)4 * 128 * 128 * 2);
    unsigned short* wt_out = (unsigned short*)alloc((size_t)64 * 128 * 2);
    unsigned short* Hbf    = (unsigned short*)alloc((size_t)n * 128 * 2);  // GEMM out
    unsigned short* Abf    = (unsigned short*)alloc((size_t)n * 128 * 2);  // activations
    unsigned short* enc    = (unsigned short*)alloc((size_t)n * 64 * 2);   // bf16 enc

    // ---- CSR build (int-only atomics) ----
    k_zero<<<NB, 256, 0, stream>>>(hist, n);
    k_hist<<<nb_E, 256, 0, stream>>>(col, hist, E);
    k_scan1<<<NB, 256, 0, stream>>>(hist, rowptr, bsum, n);
    k_scan2<<<1, 256, 0, stream>>>(bsum, boff, NB, rowptr, n);
    k_scan3<<<NB, 256, 0, stream>>>(rowptr, boff, cursor, n);
    k_place<<<nb_E, 256, 0, stream>>>(row, col, ew, cursor, pairs, E);
    k_deg<<<(n * 4 + 255) / 256, 256, 0, stream>>>(pairs, rowptr, dinv, n);

    // ---- weight prep (f32 -> bf16, transposed [N][K]) ----
    k_wt<<<(64 * 128 + 255) / 256, 256, 0, stream>>>(W_in, wt_in, 64, 128);
    for (int i = 0; i < 4; i++)
        k_wt<<<(128 * 128 + 255) / 256, 256, 0, stream>>>(
            W_hid + (size_t)i * 128 * 128, wt_hid + (size_t)i * 128 * 128, 128, 128);
    k_wt<<<(128 * 64 + 255) / 256, 256, 0, stream>>>(W_out, wt_out, 128, 64);

    // ---- layer 1: 64 -> 128 (x f32 in, converted in GEMM staging) ----
    k_gemm_mfma<64, 128, false><<<gb, 256, 0, stream>>>(x, wt_in, Hbf, n);
    k_aggregate128<true><<<ab, 256, 0, stream>>>(Hbf, pairs, rowptr, dinv, b_in,
                                                 (unsigned*)Abf, n);

    // ---- 4 hidden layers: 128 -> 128 ----
    for (int i = 0; i < 4; i++) {
        k_gemm_mfma<128, 128, true><<<gb, 256, 0, stream>>>(
            Abf, wt_hid + (size_t)i * 128 * 128, Hbf, n);
        k_aggregate128<true><<<ab, 256, 0, stream>>>(
            Hbf, pairs, rowptr, dinv, b_hid + (size_t)i * 128, (unsigned*)Abf, n);
    }

    // ---- output layer: 128 -> 64 ----
    k_gemm_mfma<128, 64, true><<<gb, 256, 0, stream>>>(Abf, wt_out, Hbf, n);
    k_aggregate64<<<(n + 7) / 8, 256, 0, stream>>>(Hbf, pairs, rowptr, dinv, b_out,
                                                   (unsigned*)enc, n);

    // ---- decoder ----
    k_decode<<<(M * 8 + 255) / 256, 256, 0, stream>>>(enc, eli, M, (float*)d_out);
}

// Round 10
// 671.951 us; speedup vs baseline: 2.4227x; 1.1365x over previous
//
#include <hip/hip_runtime.h>
#include <hip/hip_bf16.h>
#include <math.h>

// ---------------------------------------------------------------------------
// GCN link-prediction encoder: 6 GCN layers + dot-product decoder.
// R9 (on R7 base, 764us): (1) k_place atomic-free — slot = rowptr[col] +
// pos[e], where pos is the fetch-add return captured during k_hist; the
// scattered int2 stores no longer wait on an LLC atomic round-trip.
// (2) 6 k_wt launches merged into one k_wtall.
// ---------------------------------------------------------------------------

using bf16x8 = __attribute__((ext_vector_type(8))) short;  // 8 bf16 = 4 VGPRs
using f32x4  = __attribute__((ext_vector_type(4))) float;

__device__ inline unsigned f2bf_bits(float f) {            // RNE f32 -> bf16
    unsigned u = __float_as_uint(f);
    return (u + 0x7fffu + ((u >> 16) & 1u)) >> 16;
}
__device__ inline float bflo(unsigned w) { return __uint_as_float(w << 16); }
__device__ inline float bfhi(unsigned w) { return __uint_as_float(w & 0xffff0000u); }

// ---------------- CSR build (int-only atomics) ----------------

__global__ void k_zero(int* __restrict__ hist, int n) {
    int i = blockIdx.x * 256 + threadIdx.x;
    if (i < n) hist[i] = 0;
}

// histogram + per-edge slot reservation (fetch-add return)
__global__ void k_hist(const int* __restrict__ col, int* __restrict__ hist,
                       int* __restrict__ pos, int E) {
    int i = blockIdx.x * 256 + threadIdx.x;
    if (i < E) pos[i] = atomicAdd(&hist[col[i]], 1);
}

__global__ __launch_bounds__(256) void k_scan1(const int* __restrict__ hist,
                                               int* __restrict__ rowptr,
                                               int* __restrict__ bsum, int n) {
    __shared__ int lds[256];
    int t = threadIdx.x;
    int idx = blockIdx.x * 256 + t;
    int v = (idx < n) ? hist[idx] : 0;
    lds[t] = v; __syncthreads();
    for (int off = 1; off < 256; off <<= 1) {
        int x = (t >= off) ? lds[t - off] : 0;
        __syncthreads();
        lds[t] += x;
        __syncthreads();
    }
    if (idx < n) rowptr[idx] = lds[t] - v;
    if (t == 255) bsum[blockIdx.x] = lds[255];
}

__global__ __launch_bounds__(256) void k_scan2(const int* __restrict__ bsum,
                                               int* __restrict__ boff, int nb,
                                               int* __restrict__ rowptr, int n) {
    __shared__ int lds[256];
    int t = threadIdx.x;
    int carry = 0;
    for (int base = 0; base < nb; base += 256) {
        int v = (base + t < nb) ? bsum[base + t] : 0;
        lds[t] = v; __syncthreads();
        for (int off = 1; off < 256; off <<= 1) {
            int x = (t >= off) ? lds[t - off] : 0;
            __syncthreads();
            lds[t] += x;
            __syncthreads();
        }
        if (base + t < nb) boff[base + t] = carry + lds[t] - v;
        carry += lds[255];
        __syncthreads();
    }
    if (t == 0) rowptr[n] = carry;
}

__global__ void k_scan3(int* __restrict__ rowptr, const int* __restrict__ boff, int n) {
    int i = blockIdx.x * 256 + threadIdx.x;
    if (i < n) rowptr[i] += boff[blockIdx.x];
}

// place edges col-sorted, storing {row, ew} — NO atomics (slot precomputed)
__global__ void k_place(const int* __restrict__ row, const int* __restrict__ col,
                        const float* __restrict__ ew, const int* __restrict__ rowptr,
                        const int* __restrict__ pos, int2* __restrict__ pairs, int E) {
    int e = blockIdx.x * 256 + threadIdx.x;
    if (e >= E) return;
    int c = col[e];
    int slot = rowptr[c] + pos[e];
    pairs[slot] = make_int2(row[e], __float_as_int(ew[e]));
}

// dinv[g] = rsqrt(1 + sum ew over g's segment) — 4 lanes per node
__global__ void k_deg(const int2* __restrict__ pairs, const int* __restrict__ rowptr,
                      float* __restrict__ dinv, int n) {
    int t = blockIdx.x * 256 + threadIdx.x;
    int g = t >> 2, sub = t & 3;
    if (g >= n) return;
    int s = rowptr[g], e = rowptr[g + 1];
    float acc = 0.f;
    for (int i = s + sub; i < e; i += 4) acc += __int_as_float(pairs[i].y);
    acc += __shfl_xor(acc, 1, 4);
    acc += __shfl_xor(acc, 2, 4);
    if (sub == 0) dinv[g] = rsqrtf(1.f + acc);
}

// ---------------- weight prep: all weights, one launch ----------------
// W[K][N] f32 -> Wt[N][K] bf16 for W_in(64x128), W_hid(4x128x128), W_out(128x64)
__global__ void k_wtall(const float* __restrict__ W_in, const float* __restrict__ W_hid,
                        const float* __restrict__ W_out,
                        unsigned short* __restrict__ wt_in,
                        unsigned short* __restrict__ wt_hid,
                        unsigned short* __restrict__ wt_out) {
    int i = blockIdx.x * 256 + threadIdx.x;
    if (i < 8192) {                       // W_in: K=64, N=128
        int k = i / 128, nn = i % 128;
        wt_in[nn * 64 + k] = (unsigned short)f2bf_bits(W_in[i]);
    } else if (i < 73728) {               // W_hid: 4 x (K=128, N=128)
        int j = i - 8192;
        int l = j >> 14, r = j & 16383;
        int k = r / 128, nn = r % 128;
        wt_hid[l * 16384 + nn * 128 + k] = (unsigned short)f2bf_bits(W_hid[j]);
    } else if (i < 81920) {               // W_out: K=128, N=64
        int j = i - 73728;
        int k = j / 64, nn = j % 64;
        wt_out[nn * 128 + k] = (unsigned short)f2bf_bits(W_out[j]);
    }
}

// ---------------- MFMA GEMM: H = X @ W, bf16 in, f32 acc, bf16 out --------
// 128-row tile, 256 threads = 4 waves, wave w does rows [w*32, w*32+32).
// X and Wt staged in LDS (bf16, XOR-swizzled: byte ^= (row&7)<<4).
template <int K, int N, bool IN_BF16>
__global__ __launch_bounds__(256, 2) void k_gemm_mfma(
    const void* __restrict__ Xv, const unsigned short* __restrict__ Wt,
    unsigned short* __restrict__ H, int n)
{
    constexpr int NREP = N / 16;
    constexpr int KC   = K / 8;          // 16B chunks per row
    __shared__ char lds[128 * K * 2 + N * K * 2];
    char* Xs = lds;
    char* Ws = lds + 128 * K * 2;

    const int row0 = blockIdx.x * 128;
    const int tid  = threadIdx.x;

    for (int c = tid; c < 128 * KC; c += 256) {
        int r = c / KC, kc = c % KC;
        int gr = row0 + r;
        bf16x8 v = {0, 0, 0, 0, 0, 0, 0, 0};
        if (gr < n) {
            if constexpr (IN_BF16) {
                v = *(const bf16x8*)((const unsigned short*)Xv + (size_t)gr * K + kc * 8);
            } else {
                const float* xp = (const float*)Xv + (size_t)gr * K + kc * 8;
                float4 a = *(const float4*)xp;
                float4 b = *(const float4*)(xp + 4);
                v[0] = (short)f2bf_bits(a.x); v[1] = (short)f2bf_bits(a.y);
                v[2] = (short)f2bf_bits(a.z); v[3] = (short)f2bf_bits(a.w);
                v[4] = (short)f2bf_bits(b.x); v[5] = (short)f2bf_bits(b.y);
                v[6] = (short)f2bf_bits(b.z); v[7] = (short)f2bf_bits(b.w);
            }
        }
        *(bf16x8*)(Xs + ((r * (K * 2) + kc * 16) ^ ((r & 7) << 4))) = v;
    }
    for (int c = tid; c < N * KC; c += 256) {
        int r = c / KC, kc = c % KC;
        bf16x8 v = *(const bf16x8*)(Wt + (size_t)r * K + kc * 8);
        *(bf16x8*)(Ws + ((r * (K * 2) + kc * 16) ^ ((r & 7) << 4))) = v;
    }
    __syncthreads();

    const int wv   = tid >> 6;
    const int lane = tid & 63;
    const int lr   = lane & 15;
    const int lk   = lane >> 4;

    f32x4 acc[2][NREP];
    #pragma unroll
    for (int m = 0; m < 2; m++)
        #pragma unroll
        for (int j = 0; j < NREP; j++)
            acc[m][j] = (f32x4){0.f, 0.f, 0.f, 0.f};

    #pragma unroll
    for (int kk = 0; kk < K / 32; kk++) {
        int kc = kk * 4 + lk;
        bf16x8 af[2];
        #pragma unroll
        for (int m = 0; m < 2; m++) {
            int r = wv * 32 + m * 16 + lr;
            af[m] = *(const bf16x8*)(Xs + ((r * (K * 2) + kc * 16) ^ ((r & 7) << 4)));
        }
        #pragma unroll
        for (int j = 0; j < NREP; j++) {
            int r = j * 16 + lr;
            bf16x8 bfr = *(const bf16x8*)(Ws + ((r * (K * 2) + kc * 16) ^ ((r & 7) << 4)));
            acc[0][j] = __builtin_amdgcn_mfma_f32_16x16x32_bf16(af[0], bfr, acc[0][j], 0, 0, 0);
            acc[1][j] = __builtin_amdgcn_mfma_f32_16x16x32_bf16(af[1], bfr, acc[1][j], 0, 0, 0);
        }
    }

    #pragma unroll
    for (int m = 0; m < 2; m++) {
        #pragma unroll
        for (int j = 0; j < NREP; j++) {
            #pragma unroll
            for (int rr = 0; rr < 4; rr++) {
                int gr = row0 + wv * 32 + m * 16 + lk * 4 + rr;
                if (gr < n)
                    H[(size_t)gr * N + j * 16 + lr] = (unsigned short)f2bf_bits(acc[m][j][rr]);
            }
        }
    }
}

// ---------------- gather-aggregate (OC=128): on-the-fly norm --------------
// Out[c] = act( dinv[c]^2*H[c] + sum_e dinv[row]*ew*dinv[c]*H[row[e]] + b )
// one wave per node; pairs/dinv loads are wave-uniform broadcasts.
template <bool RELU>
__global__ __launch_bounds__(256) void k_aggregate128(
    const unsigned short* __restrict__ H, const int2* __restrict__ pairs,
    const int* __restrict__ rowptr, const float* __restrict__ dinv,
    const float* __restrict__ bias, unsigned* __restrict__ Out, int n)
{
    const int lane = threadIdx.x & 63;
    const int w    = threadIdx.x >> 6;
    int nd = blockIdx.x * 4 + w;
    if (nd >= n) return;
    int s  = rowptr[nd];
    int en = rowptr[nd + 1];
    float d  = dinv[nd];
    float d2 = d * d;

    const unsigned* Hu = (const unsigned*)H;
    unsigned sw = Hu[(size_t)nd * 64 + lane];
    float ax = d2 * bflo(sw), ay = d2 * bfhi(sw);
    int e = s;
    for (; e + 8 <= en; e += 8) {               // 8-deep gather pipeline
        int2 pp[8]; float dv[8]; unsigned gv[8];
        #pragma unroll
        for (int u = 0; u < 8; u++) pp[u] = pairs[e + u];
        #pragma unroll
        for (int u = 0; u < 8; u++) dv[u] = dinv[pp[u].x];
        #pragma unroll
        for (int u = 0; u < 8; u++) gv[u] = Hu[(size_t)pp[u].x * 64 + lane];
        #pragma unroll
        for (int u = 0; u < 8; u++) {
            float nm = dv[u] * __int_as_float(pp[u].y) * d;
            ax = fmaf(nm, bflo(gv[u]), ax);
            ay = fmaf(nm, bfhi(gv[u]), ay);
        }
    }
    for (; e < en; e++) {
        int2 p = pairs[e];
        float nm = dinv[p.x] * __int_as_float(p.y) * d;
        unsigned g = Hu[(size_t)p.x * 64 + lane];
        ax = fmaf(nm, bflo(g), ax);
        ay = fmaf(nm, bfhi(g), ay);
    }
    float2 bb = reinterpret_cast<const float2*>(bias)[lane];
    ax += bb.x; ay += bb.y;
    if (RELU) { ax = fmaxf(ax, 0.f); ay = fmaxf(ay, 0.f); }
    Out[(size_t)nd * 64 + lane] = f2bf_bits(ax) | (f2bf_bits(ay) << 16);
}

// ---------------- gather-aggregate (OC=64, bf16 out): 2 nodes per wave ----
__global__ __launch_bounds__(256) void k_aggregate64(
    const unsigned short* __restrict__ H, const int2* __restrict__ pairs,
    const int* __restrict__ rowptr, const float* __restrict__ dinv,
    const float* __restrict__ bias, unsigned* __restrict__ Out, int n)
{
    const int lane = threadIdx.x & 63;
    const int w    = threadIdx.x >> 6;
    const int li   = lane & 31;                 // uint index within row (32*4B=128B)
    int nd = (blockIdx.x * 4 + w) * 2 + (lane >> 5);
    if (nd >= n) return;
    int s  = rowptr[nd];
    int en = rowptr[nd + 1];
    float d  = dinv[nd];
    float d2 = d * d;

    const unsigned* Hu = (const unsigned*)H;    // 32 uints per row
    unsigned sw = Hu[(size_t)nd * 32 + li];
    float ax = d2 * bflo(sw), ay = d2 * bfhi(sw);
    int e = s;
    for (; e + 8 <= en; e += 8) {
        int2 pp[8]; float dv[8]; unsigned gv[8];
        #pragma unroll
        for (int u = 0; u < 8; u++) pp[u] = pairs[e + u];
        #pragma unroll
        for (int u = 0; u < 8; u++) dv[u] = dinv[pp[u].x];
        #pragma unroll
        for (int u = 0; u < 8; u++) gv[u] = Hu[(size_t)pp[u].x * 32 + li];
        #pragma unroll
        for (int u = 0; u < 8; u++) {
            float nm = dv[u] * __int_as_float(pp[u].y) * d;
            ax = fmaf(nm, bflo(gv[u]), ax);
            ay = fmaf(nm, bfhi(gv[u]), ay);
        }
    }
    for (; e < en; e++) {
        int2 p = pairs[e];
        float nm = dinv[p.x] * __int_as_float(p.y) * d;
        unsigned g = Hu[(size_t)p.x * 32 + li];
        ax = fmaf(nm, bflo(g), ax);
        ay = fmaf(nm, bfhi(g), ay);
    }
    float2 bb = reinterpret_cast<const float2*>(bias)[li];
    ax += bb.x; ay += bb.y;
    Out[(size_t)nd * 32 + li] = f2bf_bits(ax) | (f2bf_bits(ay) << 16);  // enc bf16
}

// logits = sigmoid(dot(enc[a], enc[b])) — 8 lanes/pair, bf16 enc (128B rows)
__global__ void k_decode(const unsigned short* __restrict__ enc,
                         const int* __restrict__ eli, int M, float* __restrict__ out)
{
    int gid  = blockIdx.x * 256 + threadIdx.x;
    int pair = gid >> 3;
    int l    = gid & 7;
    if (pair >= M) return;
    int a = eli[pair];
    int b = eli[M + pair];
    const uint4* E4 = (const uint4*)enc;        // 8 uint4 per 64-ch row
    uint4 va = E4[(size_t)a * 8 + l];
    uint4 vb = E4[(size_t)b * 8 + l];
    float s = 0.f;
    s = fmaf(bflo(va.x), bflo(vb.x), s); s = fmaf(bfhi(va.x), bfhi(vb.x), s);
    s = fmaf(bflo(va.y), bflo(vb.y), s); s = fmaf(bfhi(va.y), bfhi(vb.y), s);
    s = fmaf(bflo(va.z), bflo(vb.z), s); s = fmaf(bfhi(va.z), bfhi(vb.z), s);
    s = fmaf(bflo(va.w), bflo(vb.w), s); s = fmaf(bfhi(va.w), bfhi(vb.w), s);
    s += __shfl_xor(s, 4, 8);
    s += __shfl_xor(s, 2, 8);
    s += __shfl_xor(s, 1, 8);
    if (l == 0) out[pair] = 1.f / (1.f + expf(-s));
}

extern "C" void kernel_launch(void* const* d_in, const int* in_sizes, int n_in,
                              void* d_out, int out_size, void* d_ws, size_t ws_size,
                              hipStream_t stream)
{
    const float* x     = (const float*)d_in[0];
    const int*   ei    = (const int*)d_in[1];
    const float* ew    = (const float*)d_in[2];
    const int*   eli   = (const int*)d_in[3];
    const float* W_in  = (const float*)d_in[4];
    const float* b_in  = (const float*)d_in[5];
    const float* W_hid = (const float*)d_in[6];
    const float* b_hid = (const float*)d_in[7];
    const float* W_out = (const float*)d_in[8];
    const float* b_out = (const float*)d_in[9];

    const int n = in_sizes[0] / 64;
    const int E = in_sizes[1] / 2;
    const int M = in_sizes[3] / 2;
    const int* row = ei;
    const int* col = ei + E;

    const int NB   = (n + 255) / 256;
    const int nb_E = (E + 255) / 256;
    const int gb   = (n + 127) / 128;
    const int ab   = (n + 3) / 4;

    // ---- workspace layout (256B-aligned regions) ----
    char* basep = (char*)d_ws;
    size_t off = 0;
    auto alloc = [&](size_t bytes) {
        char* p = basep + off; off = (off + bytes + 255) & ~(size_t)255; return p; };
    float* dinv   = (float*)alloc((size_t)n * 4);
    int*   hist   = (int*)  alloc((size_t)n * 4);
    int*   rowptr = (int*)  alloc((size_t)(n + 1) * 4);
    int*   pos    = (int*)  alloc((size_t)E * 4);
    int*   bsum   = (int*)  alloc(1024 * 4);
    int*   boff   = (int*)  alloc(1024 * 4);
    int2*  pairs  = (int2*) alloc((size_t)E * 8);
    unsigned short* wt_in  = (unsigned short*)alloc((size_t)128 * 64 * 2);
    unsigned short* wt_hid = (unsigned short*)alloc((size_t)4 * 128 * 128 * 2);
    unsigned short* wt_out = (unsigned short*)alloc((size_t)64 * 128 * 2);
    unsigned short* Hbf    = (unsigned short*)alloc((size_t)n * 128 * 2);  // GEMM out
    unsigned short* Abf    = (unsigned short*)alloc((size_t)n * 128 * 2);  // activations
    unsigned short* enc    = (unsigned short*)alloc((size_t)n * 64 * 2);   // bf16 enc

    // ---- CSR build (atomics only in k_hist; place is atomic-free) ----
    k_zero<<<NB, 256, 0, stream>>>(hist, n);
    k_hist<<<nb_E, 256, 0, stream>>>(col, hist, pos, E);
    k_scan1<<<NB, 256, 0, stream>>>(hist, rowptr, bsum, n);
    k_scan2<<<1, 256, 0, stream>>>(bsum, boff, NB, rowptr, n);
    k_scan3<<<NB, 256, 0, stream>>>(rowptr, boff, n);
    k_place<<<nb_E, 256, 0, stream>>>(row, col, ew, rowptr, pos, pairs, E);
    k_deg<<<(n * 4 + 255) / 256, 256, 0, stream>>>(pairs, rowptr, dinv, n);

    // ---- weight prep (single launch) ----
    k_wtall<<<320, 256, 0, stream>>>(W_in, W_hid, W_out, wt_in, wt_hid, wt_out);

    // ---- layer 1: 64 -> 128 (x f32 in, converted in GEMM staging) ----
    k_gemm_mfma<64, 128, false><<<gb, 256, 0, stream>>>(x, wt_in, Hbf, n);
    k_aggregate128<true><<<ab, 256, 0, stream>>>(Hbf, pairs, rowptr, dinv, b_in,
                                                 (unsigned*)Abf, n);

    // ---- 4 hidden layers: 128 -> 128 ----
    for (int i = 0; i < 4; i++) {
        k_gemm_mfma<128, 128, true><<<gb, 256, 0, stream>>>(
            Abf, wt_hid + (size_t)i * 128 * 128, Hbf, n);
        k_aggregate128<true><<<ab, 256, 0, stream>>>(
            Hbf, pairs, rowptr, dinv, b_hid + (size_t)i * 128, (unsigned*)Abf, n);
    }

    // ---- output layer: 128 -> 64 ----
    k_gemm_mfma<128, 64, true><<<gb, 256, 0, stream>>>(Abf, wt_out, Hbf, n);
    k_aggregate64<<<(n + 7) / 8, 256, 0, stream>>>(Hbf, pairs, rowptr, dinv, b_out,
                                                   (unsigned*)enc, n);

    // ---- decoder ----
    k_decode<<<(M * 8 + 255) / 256, 256, 0, stream>>>(enc, eli, M, (float*)d_out);
}